// Round 1
// baseline (35.649 us; speedup 1.0000x reference)
//
#include <hip/hip_runtime.h>

namespace {
constexpr int kB      = 8;
constexpr int kN      = 1024;
constexpr int kM      = 24;          // FIR taps j = 1..24
constexpr int kP      = 80;          // frame period
constexpr int kT      = kN * kP;     // 81920
constexpr int kTaylor = 20;
constexpr int kTB     = 2560;        // time tile per block
constexpr int kBlkT   = kT / kTB;    // 32 tiles per batch
constexpr int kHalo   = kTaylor * kM;    // 480
constexpr int kE      = kTB + kHalo;     // 3040 extended samples
constexpr int kChunks = kE / 4;          // 760 4-sample chunks
constexpr int kThreads = 768;
constexpr int kFrames  = 40;             // staged coefficient frames
}

__global__ __launch_bounds__(kThreads, 1)
void mlsa_taylor_kernel(const float* __restrict__ x,
                        const float* __restrict__ mc,
                        const float* __restrict__ av,
                        const float* __restrict__ wv,
                        float* __restrict__ out) {
  __shared__ float sA[kE];
  __shared__ float sB[kE];
  __shared__ float scb[kFrames][kM + 1];   // base coeff per frame
  __shared__ float scd[kFrames][kM + 1];   // delta to next frame

  const int tid = (int)threadIdx.x;
  const int blk = (int)blockIdx.x;
  const int b   = blk / kBlkT;
  const int t0  = (blk % kBlkT) * kTB;
  const int fbase = t0 / kP - kHalo / kP;  // (t0 - 480)/80, exact

  // ---- stage interpolation coefficients (base, delta) ----
  const float* mcb = mc + (size_t)b * kN * (kM + 1);
  for (int s = tid; s < kFrames * (kM + 1); s += kThreads) {
    const int lf = s / (kM + 1);
    const int j  = s - lf * (kM + 1);
    const int f  = fbase + lf;
    const int f0 = f < 0 ? 0 : (f > kN - 1 ? kN - 1 : f);
    const int f1 = (f + 1) < 0 ? 0 : ((f + 1) > kN - 1 ? kN - 1 : f + 1);
    const float vb = mcb[f0 * (kM + 1) + j];
    const float vn = mcb[f1 * (kM + 1) + j];
    scb[lf][j] = vb;
    scd[lf][j] = vn - vb;
  }

  // ---- stage x into sA (zeros where global t < 0) ----
  {
    const int e4 = tid * 4;
    if (e4 < kE) {
      const int t = t0 - kHalo + e4;
      float4 v = make_float4(0.f, 0.f, 0.f, 0.f);
      if (t >= 0) v = *reinterpret_cast<const float4*>(x + (size_t)b * kT + t);
      *reinterpret_cast<float4*>(&sA[e4]) = v;
      if (t < 0) *reinterpret_cast<float4*>(&sB[e4]) = v;   // keep zeros in both buffers
    }
  }
  __syncthreads();

  const int  c      = tid;
  const bool valid  = c < kChunks;
  const int  e0     = 4 * c;
  const int  tg     = t0 - kHalo + e0;     // global t of this chunk
  const bool act    = valid && (tg >= 0);
  const bool is_out = valid && (c >= kHalo / 4);

  float cbr[kM + 1], cdr[kM + 1], wfr[4];
  if (act) {
    const int lf = c / 20;                 // 4c/80 — chunk never crosses a frame
    const int ph = (4 * c) % kP;
#pragma unroll
    for (int j = 0; j <= kM; ++j) { cbr[j] = scb[lf][j]; cdr[j] = scd[lf][j]; }
#pragma unroll
    for (int q = 0; q < 4; ++q) wfr[q] = (float)(ph + q) * (1.0f / kP);
  }

  float yacc[4] = {0.f, 0.f, 0.f, 0.f};
  if (is_out) {
    const float a0 = av[0];
#pragma unroll
    for (int q = 0; q < 4; ++q) yacc[q] = a0 * sA[e0 + q];
  }

  float* src = sA;
  float* dst = sB;
#pragma unroll 1
  for (int i = 1; i <= kTaylor; ++i) {
    const float wi = wv[i];
    const float ai = av[i];
    __syncthreads();                       // one barrier per stage (double buffer)
    if (act && c >= 6 * i) {               // shrinking valid range: e >= 24*i
      float win[28];                       // samples [e0-24 .. e0+3]
#pragma unroll
      for (int s = 0; s < 7; ++s) {
        const float4 v = *reinterpret_cast<const float4*>(src + e0 - kM + 4 * s);
        win[4 * s + 0] = v.x; win[4 * s + 1] = v.y;
        win[4 * s + 2] = v.z; win[4 * s + 3] = v.w;
      }
      float accb[4] = {0.f, 0.f, 0.f, 0.f};
      float accd[4] = {0.f, 0.f, 0.f, 0.f};
#pragma unroll
      for (int j = 1; j <= kM; ++j) {
#pragma unroll
        for (int q = 0; q < 4; ++q) {
          const float v = win[kM + q - j];
          accb[q] = fmaf(v, cbr[j], accb[q]);
          accd[q] = fmaf(v, cdr[j], accd[q]);
        }
      }
      float cur[4];
#pragma unroll
      for (int q = 0; q < 4; ++q)
        cur[q] = (accb[q] + wfr[q] * accd[q]) * wi;
      float4 cv;
      cv.x = cur[0]; cv.y = cur[1]; cv.z = cur[2]; cv.w = cur[3];
      *reinterpret_cast<float4*>(dst + e0) = cv;
      if (is_out) {
#pragma unroll
        for (int q = 0; q < 4; ++q) yacc[q] += ai * cur[q];
      }
    }
    float* tmp = src; src = dst; dst = tmp;
  }

  if (is_out) {
    float4 o;
    o.x = yacc[0] * __expf(cbr[0] + wfr[0] * cdr[0]);
    o.y = yacc[1] * __expf(cbr[0] + wfr[1] * cdr[0]);
    o.z = yacc[2] * __expf(cbr[0] + wfr[2] * cdr[0]);
    o.w = yacc[3] * __expf(cbr[0] + wfr[3] * cdr[0]);
    *reinterpret_cast<float4*>(out + (size_t)b * kT + tg) = o;
  }
}

extern "C" void kernel_launch(void* const* d_in, const int* in_sizes, int n_in,
                              void* d_out, int out_size, void* d_ws, size_t ws_size,
                              hipStream_t stream) {
  const float* x  = (const float*)d_in[0];
  const float* mc = (const float*)d_in[1];
  const float* a  = (const float*)d_in[2];
  const float* w  = (const float*)d_in[3];
  float* out = (float*)d_out;
  dim3 grid(kB * kBlkT);      // 256 blocks, 1 per CU
  dim3 block(kThreads);       // 768 threads = 12 waves
  hipLaunchKernelGGL(mlsa_taylor_kernel, grid, block, 0, stream,
                     x, mc, a, w, out);
}

// Round 2
// 32.346 us; speedup vs baseline: 1.1021x; 1.1021x over previous
//
#include <hip/hip_runtime.h>

namespace {
constexpr int kB      = 8;
constexpr int kN      = 1024;
constexpr int kM      = 24;          // FIR taps j = 1..24
constexpr int kP      = 80;          // frame period
constexpr int kT      = kN * kP;     // 81920
constexpr int kTaylor = 20;
constexpr int kTB     = 2560;        // time tile per block
constexpr int kBlkT   = kT / kTB;    // 32 tiles per batch
constexpr int kHalo   = kTaylor * kM;    // 480
constexpr int kE      = kTB + kHalo;     // 3040 extended samples
constexpr int kChunks = kE / 4;          // 760 4-sample chunks
constexpr int kThreads = 768;
constexpr int kFrames  = 40;             // staged coefficient frames
}

__global__ __launch_bounds__(kThreads, 3)
void mlsa_taylor_kernel(const float* __restrict__ x,
                        const float* __restrict__ mc,
                        const float* __restrict__ av,
                        const float* __restrict__ wv,
                        float* __restrict__ out) {
  __shared__ float sbuf[2][kE];            // ping-pong, indexed (stays LDS-addrspace)
  __shared__ float scb[kFrames][kM + 1];   // base coeff per frame
  __shared__ float scd[kFrames][kM + 1];   // delta to next frame
  __shared__ float s_a[kTaylor + 1];
  __shared__ float s_w[kTaylor + 1];

  const int tid = (int)threadIdx.x;
  const int blk = (int)blockIdx.x;
  const int b   = blk / kBlkT;
  const int t0  = (blk % kBlkT) * kTB;
  const int fbase = t0 / kP - kHalo / kP;

  if (tid <= kTaylor) { s_a[tid] = av[tid]; s_w[tid] = wv[tid]; }

  // ---- stage interpolation coefficients (base, delta) ----
  const float* mcb = mc + (size_t)b * kN * (kM + 1);
  for (int s = tid; s < kFrames * (kM + 1); s += kThreads) {
    const int lf = s / (kM + 1);
    const int j  = s - lf * (kM + 1);
    const int f  = fbase + lf;
    const int f0 = f < 0 ? 0 : (f > kN - 1 ? kN - 1 : f);
    const int f1 = (f + 1) < 0 ? 0 : ((f + 1) > kN - 1 ? kN - 1 : f + 1);
    const float vb = mcb[f0 * (kM + 1) + j];
    const float vn = mcb[f1 * (kM + 1) + j];
    scb[lf][j] = vb;
    scd[lf][j] = vn - vb;
  }

  // ---- stage x into sbuf[0] (zeros where global t < 0, in both buffers) ----
  {
    const int e4 = tid * 4;
    if (e4 < kE) {
      const int t = t0 - kHalo + e4;
      float4 v = make_float4(0.f, 0.f, 0.f, 0.f);
      if (t >= 0) v = *reinterpret_cast<const float4*>(x + (size_t)b * kT + t);
      *reinterpret_cast<float4*>(&sbuf[0][e4]) = v;
      if (t < 0) *reinterpret_cast<float4*>(&sbuf[1][e4]) = v;
    }
  }
  __syncthreads();

  const int  c      = tid;
  const bool valid  = c < kChunks;
  const int  e0     = 4 * c;
  const int  tg     = t0 - kHalo + e0;
  const bool act    = valid && (tg >= 0);
  const bool is_out = valid && (c >= kHalo / 4);

  // ---- per-lane effective coefficients: fold interp weight in ONCE ----
  // ceff[q][j-1] = cb[j] + w_q * cd[j]  (stage-invariant: chunk never crosses a frame)
  float ceff[4][kM];
  float wfr[4] = {0.f, 0.f, 0.f, 0.f};
  float cb0 = 0.f, cd0 = 0.f;
  if (act) {
    const int lf = c / 20;
    const int ph = (4 * c) % kP;
#pragma unroll
    for (int q = 0; q < 4; ++q) wfr[q] = (float)(ph + q) * (1.0f / kP);
    cb0 = scb[lf][0];
    cd0 = scd[lf][0];
#pragma unroll
    for (int j = 1; j <= kM; ++j) {
      const float vb = scb[lf][j];
      const float vd = scd[lf][j];
#pragma unroll
      for (int q = 0; q < 4; ++q) ceff[q][j - 1] = fmaf(wfr[q], vd, vb);
    }
  }

  float yacc[4] = {0.f, 0.f, 0.f, 0.f};
  if (is_out) {
    const float a0 = s_a[0];
#pragma unroll
    for (int q = 0; q < 4; ++q) yacc[q] = a0 * sbuf[0][e0 + q];
  }

#pragma unroll 1
  for (int i = 1; i <= kTaylor; ++i) {
    const int pb   = (i - 1) & 1;
    const int cbuf = i & 1;
    const float wi = s_w[i];
    const float ai = s_a[i];
    __syncthreads();                       // one barrier per stage (double buffer)
    if (act && c >= 6 * i) {               // shrinking valid range: e >= 24*i
      float win[28];                       // samples [e0-24 .. e0+3]
#pragma unroll
      for (int s = 0; s < 7; ++s) {
        const float4 v = *reinterpret_cast<const float4*>(&sbuf[pb][e0 - kM + 4 * s]);
        win[4 * s + 0] = v.x; win[4 * s + 1] = v.y;
        win[4 * s + 2] = v.z; win[4 * s + 3] = v.w;
      }
      float acc[4] = {0.f, 0.f, 0.f, 0.f};
#pragma unroll
      for (int j = 1; j <= kM; ++j) {
#pragma unroll
        for (int q = 0; q < 4; ++q)
          acc[q] = fmaf(win[kM + q - j], ceff[q][j - 1], acc[q]);
      }
      float cur[4];
#pragma unroll
      for (int q = 0; q < 4; ++q) cur[q] = acc[q] * wi;
      float4 cv;
      cv.x = cur[0]; cv.y = cur[1]; cv.z = cur[2]; cv.w = cur[3];
      *reinterpret_cast<float4*>(&sbuf[cbuf][e0]) = cv;
      // yacc garbage for halo lanes is never stored (is_out implies c >= 120 >= 6i)
#pragma unroll
      for (int q = 0; q < 4; ++q) yacc[q] += ai * cur[q];
    }
  }

  if (is_out) {
    float4 o;
    o.x = yacc[0] * __expf(cb0 + wfr[0] * cd0);
    o.y = yacc[1] * __expf(cb0 + wfr[1] * cd0);
    o.z = yacc[2] * __expf(cb0 + wfr[2] * cd0);
    o.w = yacc[3] * __expf(cb0 + wfr[3] * cd0);
    *reinterpret_cast<float4*>(out + (size_t)b * kT + tg) = o;
  }
}

extern "C" void kernel_launch(void* const* d_in, const int* in_sizes, int n_in,
                              void* d_out, int out_size, void* d_ws, size_t ws_size,
                              hipStream_t stream) {
  const float* x  = (const float*)d_in[0];
  const float* mc = (const float*)d_in[1];
  const float* a  = (const float*)d_in[2];
  const float* w  = (const float*)d_in[3];
  float* out = (float*)d_out;
  dim3 grid(kB * kBlkT);      // 256 blocks, 1 per CU
  dim3 block(kThreads);       // 768 threads = 12 waves
  hipLaunchKernelGGL(mlsa_taylor_kernel, grid, block, 0, stream,
                     x, mc, a, w, out);
}

// Round 3
// 30.068 us; speedup vs baseline: 1.1856x; 1.0757x over previous
//
#include <hip/hip_runtime.h>

namespace {
constexpr int kB      = 8;
constexpr int kN      = 1024;
constexpr int kM      = 24;          // FIR taps j = 1..24
constexpr int kP      = 80;          // frame period
constexpr int kT      = kN * kP;     // 81920
constexpr int kTaylor = 20;
constexpr int kTB     = 1280;        // time tile per block (2 blocks/CU)
constexpr int kBlkT   = kT / kTB;    // 64 tiles per batch
constexpr int kHalo   = kTaylor * kM;    // 480
constexpr int kE      = kTB + kHalo;     // 1760 extended samples
constexpr int kChunks = kE / 4;          // 440 4-sample chunks
constexpr int kThreads = 448;            // 7 waves
constexpr int kFrames  = 22;             // staged coefficient frames (lf 0..21)
}

__global__ __launch_bounds__(kThreads, 4)
void mlsa_taylor_kernel(const float* __restrict__ x,
                        const float* __restrict__ mc,
                        const float* __restrict__ av,
                        const float* __restrict__ wv,
                        float* __restrict__ out) {
  __shared__ float sbuf[2][kE];            // ping-pong neighbor-exchange buffers
  __shared__ float scb[kFrames][kM + 1];   // base coeff per frame
  __shared__ float scd[kFrames][kM + 1];   // delta to next frame
  __shared__ float s_a[kTaylor + 1];
  __shared__ float s_w[kTaylor + 1];

  const int tid = (int)threadIdx.x;
  const int blk = (int)blockIdx.x;
  const int b   = blk / kBlkT;
  const int t0  = (blk % kBlkT) * kTB;
  const int fbase = t0 / kP - kHalo / kP;  // t0/80 - 6

  if (tid <= kTaylor) { s_a[tid] = av[tid]; s_w[tid] = wv[tid]; }

  // ---- stage interpolation coefficients (base, delta) ----
  const float* mcb = mc + (size_t)b * kN * (kM + 1);
  for (int s = tid; s < kFrames * (kM + 1); s += kThreads) {
    const int lf = s / (kM + 1);
    const int j  = s - lf * (kM + 1);
    const int f  = fbase + lf;
    const int f0 = f < 0 ? 0 : (f > kN - 1 ? kN - 1 : f);
    const int f1 = (f + 1) < 0 ? 0 : ((f + 1) > kN - 1 ? kN - 1 : f + 1);
    const float vb = mcb[f0 * (kM + 1) + j];
    const float vn = mcb[f1 * (kM + 1) + j];
    scb[lf][j] = vb;
    scd[lf][j] = vn - vb;
  }

  const int  c      = tid;
  const bool valid  = c < kChunks;
  const int  e0     = 4 * c;
  const int  tg     = t0 - kHalo + e0;
  const bool act    = valid && (tg >= 0);
  const bool is_out = valid && (c >= kHalo / 4);

  // ---- load own x chunk into registers; publish to sbuf[0]; zeros persist for tg<0 ----
  float cur[4] = {0.f, 0.f, 0.f, 0.f};
  if (act) {
    const float4 v = *reinterpret_cast<const float4*>(x + (size_t)b * kT + tg);
    cur[0] = v.x; cur[1] = v.y; cur[2] = v.z; cur[3] = v.w;
  }
  if (valid) {
    float4 v;
    v.x = cur[0]; v.y = cur[1]; v.z = cur[2]; v.w = cur[3];
    *reinterpret_cast<float4*>(&sbuf[0][e0]) = v;
    if (tg < 0) {  // keep zeros in the other buffer too (halo of first tile)
      *reinterpret_cast<float4*>(&sbuf[1][e0]) = make_float4(0.f, 0.f, 0.f, 0.f);
    }
  }
  __syncthreads();

  // ---- per-lane effective coefficients (stage-invariant) ----
  float ceff[4][kM];
  float wfr[4] = {0.f, 0.f, 0.f, 0.f};
  float cb0 = 0.f, cd0 = 0.f;
  if (act) {
    const int lf = c / 20;                 // chunk never crosses a frame (4 | 80)
    const int ph = (4 * c) % kP;
#pragma unroll
    for (int q = 0; q < 4; ++q) wfr[q] = (float)(ph + q) * (1.0f / kP);
    cb0 = scb[lf][0];
    cd0 = scd[lf][0];
#pragma unroll
    for (int j = 1; j <= kM; ++j) {
      const float vb = scb[lf][j];
      const float vd = scd[lf][j];
#pragma unroll
      for (int q = 0; q < 4; ++q) ceff[q][j - 1] = fmaf(wfr[q], vd, vb);
    }
  }

  float yacc[4] = {0.f, 0.f, 0.f, 0.f};
  if (is_out) {
    const float a0 = s_a[0];
#pragma unroll
    for (int q = 0; q < 4; ++q) yacc[q] = a0 * cur[q];
  }

#pragma unroll 1
  for (int i = 1; i <= kTaylor; ++i) {
    const int pb   = (i - 1) & 1;
    const int cbuf = i & 1;
    const float wi = s_w[i];
    const float ai = s_a[i];
    __syncthreads();                       // separates stage i-1 writes from stage i reads
    if (act && c >= 6 * i) {               // shrinking valid range: e >= 24*i
      float win[28];                       // win[0..23] = neighbor chunks, win[24..27] = own prev
#pragma unroll
      for (int s = 0; s < 6; ++s) {
        const float4 v = *reinterpret_cast<const float4*>(&sbuf[pb][e0 - kM + 4 * s]);
        win[4 * s + 0] = v.x; win[4 * s + 1] = v.y;
        win[4 * s + 2] = v.z; win[4 * s + 3] = v.w;
      }
#pragma unroll
      for (int q = 0; q < 4; ++q) win[24 + q] = cur[q];
      float acc[4] = {0.f, 0.f, 0.f, 0.f};
#pragma unroll
      for (int j = 1; j <= kM; ++j) {
#pragma unroll
        for (int q = 0; q < 4; ++q)
          acc[q] = fmaf(win[kM + q - j], ceff[q][j - 1], acc[q]);
      }
#pragma unroll
      for (int q = 0; q < 4; ++q) cur[q] = acc[q] * wi;
      float4 cv;
      cv.x = cur[0]; cv.y = cur[1]; cv.z = cur[2]; cv.w = cur[3];
      *reinterpret_cast<float4*>(&sbuf[cbuf][e0]) = cv;
#pragma unroll
      for (int q = 0; q < 4; ++q) yacc[q] += ai * cur[q];
    }
  }

  if (is_out) {
    float4 o;
    o.x = yacc[0] * __expf(cb0 + wfr[0] * cd0);
    o.y = yacc[1] * __expf(cb0 + wfr[1] * cd0);
    o.z = yacc[2] * __expf(cb0 + wfr[2] * cd0);
    o.w = yacc[3] * __expf(cb0 + wfr[3] * cd0);
    *reinterpret_cast<float4*>(out + (size_t)b * kT + tg) = o;
  }
}

extern "C" void kernel_launch(void* const* d_in, const int* in_sizes, int n_in,
                              void* d_out, int out_size, void* d_ws, size_t ws_size,
                              hipStream_t stream) {
  const float* x  = (const float*)d_in[0];
  const float* mc = (const float*)d_in[1];
  const float* a  = (const float*)d_in[2];
  const float* w  = (const float*)d_in[3];
  float* out = (float*)d_out;
  dim3 grid(kB * kBlkT);      // 512 blocks → 2 per CU (two barrier domains overlap)
  dim3 block(kThreads);       // 448 threads = 7 waves
  hipLaunchKernelGGL(mlsa_taylor_kernel, grid, block, 0, stream,
                     x, mc, a, w, out);
}